// Round 1
// baseline (187.778 us; speedup 1.0000x reference)
//
#include <hip/hip_runtime.h>

// Problem constants (from reference):
//   e_src: [B=32, T=1024, F=4, C=256] fp32
//   d_src: [B=32, S=256] integer durations in [0, 8)
//   out:   [B=32, S=256, C=256] fp32 segment means (zeros for empty segments)

#define NB 32
#define NT 1024
#define NF 4
#define NC 256
#define NS 256

__global__ __launch_bounds__(256) void FastSpeech2Pros_83769042141888_kernel(
    const float* __restrict__ e_src,   // [B, T, F, C]
    const int*   __restrict__ d_src,   // [B, S]
    float*       __restrict__ out)     // [B, S, C]
{
    const int s = blockIdx.x;   // phone index 0..255
    const int b = blockIdx.y;   // batch index 0..31
    const int t = threadIdx.x;  // 0..255

    // --- inclusive scan of durations for this batch row (Hillis-Steele) ---
    __shared__ int cs[NS];
    cs[t] = d_src[b * NS + t];
    __syncthreads();
    #pragma unroll
    for (int off = 1; off < NS; off <<= 1) {
        int v = (t >= off) ? cs[t - off] : 0;
        __syncthreads();
        cs[t] += v;
        __syncthreads();
    }

    int end   = cs[s];
    int start = (s == 0) ? 0 : cs[s - 1];
    if (start > NT) start = NT;
    if (end   > NT) end   = NT;
    const int cnt = end - start;   // may be <= 0 -> empty segment

    // --- accumulate float4 per thread over this phone's frames ---
    // Frame layout: [F][C] = 1024 contiguous floats = 256 float4.
    // Thread t's float4 covers freq (t>>6), channels (t&63)*4 .. +3.
    float4 acc = make_float4(0.f, 0.f, 0.f, 0.f);
    const float4* base =
        (const float4*)(e_src + (size_t)b * NT * NF * NC);
    for (int fr = start; fr < end; ++fr) {
        float4 v = base[(size_t)fr * (NF * NC / 4) + t];
        acc.x += v.x; acc.y += v.y; acc.z += v.z; acc.w += v.w;
    }

    // --- cross-freq reduction: lanes t, t+64, t+128, t+192 share channels ---
    __shared__ float4 red[256];
    red[t] = acc;
    __syncthreads();

    if (t < 64) {
        float4 a0 = red[t];
        float4 a1 = red[t + 64];
        float4 a2 = red[t + 128];
        float4 a3 = red[t + 192];
        // mean over (frames, freq) == sum / (4 * cnt); zeros if empty
        const float inv = (cnt > 0) ? (1.0f / (4.0f * (float)cnt)) : 0.0f;
        float4 o;
        o.x = (a0.x + a1.x + a2.x + a3.x) * inv;
        o.y = (a0.y + a1.y + a2.y + a3.y) * inv;
        o.z = (a0.z + a1.z + a2.z + a3.z) * inv;
        o.w = (a0.w + a1.w + a2.w + a3.w) * inv;
        ((float4*)(out + ((size_t)b * NS + s) * NC))[t] = o;
    }
}

extern "C" void kernel_launch(void* const* d_in, const int* in_sizes, int n_in,
                              void* d_out, int out_size, void* d_ws, size_t ws_size,
                              hipStream_t stream) {
    const float* e_src = (const float*)d_in[0];
    const int*   d_src = (const int*)d_in[1];
    float*       out   = (float*)d_out;

    dim3 grid(NS, NB);  // one block per (phone, batch)
    FastSpeech2Pros_83769042141888_kernel<<<grid, 256, 0, stream>>>(e_src, d_src, out);
}